// Round 3
// baseline (491.617 us; speedup 1.0000x reference)
//
#include <hip/hip_runtime.h>
#include <hip/hip_bf16.h>

typedef __bf16 bf16_t;
typedef bf16_t bf16x8 __attribute__((ext_vector_type(8)));
typedef bf16_t bf16x4 __attribute__((ext_vector_type(4)));
typedef float  f32x4  __attribute__((ext_vector_type(4)));
typedef float  f32x16 __attribute__((ext_vector_type(16)));
typedef unsigned int u32;
typedef u32 u32x4 __attribute__((ext_vector_type(4)));

#define S_LEN  2048
#define DMODEL 2048
#define NH     16
#define DH     128
#define BATCH  2
#define MROWS  (BATCH * S_LEN)   // 4096

#define NEG_BIG (-1.0e30f)

__device__ __forceinline__ bf16x8 cvt8_f32_bf16(const float* __restrict__ p) {
  float4 f0 = *(const float4*)(p);
  float4 f1 = *(const float4*)(p + 4);
  bf16x8 r;
  r[0] = (bf16_t)f0.x; r[1] = (bf16_t)f0.y; r[2] = (bf16_t)f0.z; r[3] = (bf16_t)f0.w;
  r[4] = (bf16_t)f1.x; r[5] = (bf16_t)f1.y; r[6] = (bf16_t)f1.z; r[7] = (bf16_t)f1.w;
  return r;
}

// async global(16B/lane) -> LDS. Dest = wave-uniform base + lane*16 (m97/m104).
__device__ __forceinline__ void gld16(const void* g, void* l) {
  __builtin_amdgcn_global_load_lds(
      (const __attribute__((address_space(1))) void*)g,
      (__attribute__((address_space(3))) void*)l, 16, 0, 0);
}

__device__ __forceinline__ float exp2fast(float x) {
#if __has_builtin(__builtin_amdgcn_exp2f)
  return __builtin_amdgcn_exp2f(x);
#else
  return __expf(x * 0.6931471805599453f);
#endif
}

// pack two f32 -> one u32 of 2 bf16 (lo in [15:0], hi in [31:16]).
__device__ __forceinline__ u32 pack_bf16(float lo, float hi) {
  union { bf16_t h[2]; u32 w; } u;
  u.h[0] = (bf16_t)lo; u.h[1] = (bf16_t)hi;
  return u.w;
}

// ---------------- fp32 -> bf16 conversion ----------------
__global__ __launch_bounds__(256)
void cvt_bf16(const float* __restrict__ s, bf16_t* __restrict__ d, int n8) {
  int i = blockIdx.x * 256 + threadIdx.x;
  if (i < n8) *(bf16x8*)(&d[(size_t)i * 8]) = cvt8_f32_bf16(&s[(size_t)i * 8]);
}

// ------- GEMM v2: 128x128 tile, BK=64, double-buffered, 1 barrier/K-tile ----
// attn-validated schedule: STAGE(next) issued right after the barrier, in
// flight across the whole tile compute; __syncthreads' vmcnt(0) is the drain.
// LDS 64KB -> 2 blocks/CU. XOR-swizzled source+read (rule #21 involution):
// LDS(r,g) holds G(r, g^(r&7)); read granule gl at As[r*64+((gl^(r&7))*8)].
// Spreads b128 reads over all 32 banks (unswizzled uses only 16).
// Grid: 512 blocks, 1-D; XCD swizzle: XCD j <- by in {2j,2j+1} (W-panel L2 fit).
template <typename TC>
__global__ __launch_bounds__(256, 2)
void gemm_bt2(const bf16_t* __restrict__ A, const bf16_t* __restrict__ W,
              const float* __restrict__ bias, TC* __restrict__ C,
              int mode, float oscale)
{
  constexpr int K = DMODEL, N = DMODEL;
  constexpr int NT = K / 64;                  // 32 K-tiles
  __shared__ __align__(16) bf16_t As[2][128 * 64];
  __shared__ __align__(16) bf16_t Bs[2][128 * 64];
  const int tid  = threadIdx.x;
  const int wave = tid >> 6, lane = tid & 63;
  const int quad = lane >> 4, l16 = lane & 15;
  // 512 blocks = (32 bx) x (16 by); HW round-robins ids over 8 XCDs, so give
  // XCD j the two by-panels {2j, 2j+1}: bijective id -> (bx, by).
  const int id = blockIdx.x;
  const int bx = (id >> 3) & 31;
  const int by = ((id & 7) << 1) | (id >> 8);
  const int bm = bx * 128, bn = by * 128;
  const int wm = (wave >> 1) * 64, wn = (wave & 1) * 64;

  f32x4 acc[4][4] = {};

  auto STAGE = [&](int buf, int t) {
    const int k0 = t * 64;
#pragma unroll
    for (int i = 0; i < 4; ++i) {
      int c = tid + i * 256;                  // 1024 16B-chunks per operand
      int row = c >> 3, g = c & 7;
      int gc = (g ^ (row & 7)) << 3;          // pre-swizzled global granule
      gld16(&A[(size_t)(bm + row) * K + k0 + gc], &As[buf][c << 3]);
      gld16(&W[(size_t)(bn + row) * K + k0 + gc], &Bs[buf][c << 3]);
    }
  };

  STAGE(0, 0);
  int cur = 0;
  for (int t = 0; t < NT; ++t) {
    __syncthreads();                          // vmcnt(0): buf[cur] staged; all
                                              // waves done reading buf[cur^1]
    if (t + 1 < NT) STAGE(cur ^ 1, t + 1);    // in flight over the compute
    const bf16_t* as = As[cur];
    const bf16_t* bs = Bs[cur];
#pragma unroll
    for (int kk = 0; kk < 2; ++kk) {
      bf16x8 af[4], bfr[4];
#pragma unroll
      for (int i = 0; i < 4; ++i) {
        int gl = ((kk << 2) | quad) ^ (l16 & 7);   // rows&7 == l16&7
        af[i]  = *(const bf16x8*)(&as[(wm + i * 16 + l16) * 64 + gl * 8]);
        bfr[i] = *(const bf16x8*)(&bs[(wn + i * 16 + l16) * 64 + gl * 8]);
      }
#pragma unroll
      for (int mi = 0; mi < 4; ++mi)
#pragma unroll
        for (int ni = 0; ni < 4; ++ni)
          acc[mi][ni] = __builtin_amdgcn_mfma_f32_16x16x32_bf16(
              af[mi], bfr[ni], acc[mi][ni], 0, 0, 0);
    }
    cur ^= 1;
  }

#pragma unroll
  for (int mi = 0; mi < 4; ++mi) {
#pragma unroll
    for (int ni = 0; ni < 4; ++ni) {
      int col = bn + wn + ni * 16 + l16;
      float bval = bias[col];
      if (mode == 2) {
        int row0 = bm + wm + mi * 16 + quad * 4;
        int b = row0 >> 11, s = row0 & (S_LEN - 1);
        int h = col >> 7,  d = col & (DH - 1);
        size_t idx0 = (((size_t)(b * NH + h)) * DH + d) * S_LEN + s;
        if constexpr (__is_same(TC, bf16_t)) {
          bf16x4 o4;
#pragma unroll
          for (int r = 0; r < 4; ++r) o4[r] = (bf16_t)((acc[mi][ni][r] + bval) * oscale);
          *(bf16x4*)(&C[idx0]) = o4;
        } else {
#pragma unroll
          for (int r = 0; r < 4; ++r) C[idx0 + r] = (TC)((acc[mi][ni][r] + bval) * oscale);
        }
      } else {
#pragma unroll
        for (int r = 0; r < 4; ++r) {
          int row = bm + wm + mi * 16 + quad * 4 + r;
          float vv = (acc[mi][ni][r] + bval) * oscale;
          size_t idx;
          if (mode == 0) {
            idx = (size_t)row * N + col;
          } else {
            int b = row >> 11, s = row & (S_LEN - 1);
            int h = col >> 7,  d = col & (DH - 1);
            idx = (((size_t)(b * NH + h)) * S_LEN + s) * DH + d;
          }
          C[idx] = (TC)vv;
        }
      }
    }
  }
}

// ---------------- GEMM v1 (fallback paths): C = (A @ W^T + bias) * oscale ---
// m97 structure: BK=32, unpadded LDS, global_load_lds for bf16 operands.
// mode 0: C[row*N+col]; 1: [B,H,S,DH]; 2: [B,H,DH,S] (V transposed)
template <typename TA, typename TW, typename TC>
__global__ __launch_bounds__(256)
void gemm_bt(const TA* __restrict__ A, const TW* __restrict__ W,
             const float* __restrict__ bias, TC* __restrict__ C,
             int mode, float oscale)
{
  constexpr int K = DMODEL, N = DMODEL;
  __shared__ __align__(16) bf16_t As[128 * 32];
  __shared__ __align__(16) bf16_t Bs[128 * 32];
  const int tid  = threadIdx.x;
  const int wave = tid >> 6, lane = tid & 63;
  const int quad = lane >> 4, l16 = lane & 15;
  const int bm = blockIdx.x * 128, bn = blockIdx.y * 128;
  const int wm = (wave >> 1) * 64, wn = (wave & 1) * 64;

  f32x4 acc[4][4] = {};

  for (int k0 = 0; k0 < K; k0 += 32) {
    __syncthreads();
    if constexpr (__is_same(TA, float)) {
#pragma unroll
      for (int i = 0; i < 2; ++i) {
        int c = tid + i * 256, row = c >> 2, col = (c & 3) << 3;
        *(bf16x8*)(&As[row * 32 + col]) =
            cvt8_f32_bf16(&A[(size_t)(bm + row) * K + k0 + col]);
      }
    } else {
#pragma unroll
      for (int t = 0; t < 2; ++t) {
        int chunk = wave * 128 + t * 64 + lane;
        int row = chunk >> 2, col = (chunk & 3) << 3;
        gld16(&A[(size_t)(bm + row) * K + k0 + col], &As[row * 32 + col]);
      }
    }
    if constexpr (__is_same(TW, float)) {
#pragma unroll
      for (int i = 0; i < 2; ++i) {
        int c = tid + i * 256, row = c >> 2, col = (c & 3) << 3;
        *(bf16x8*)(&Bs[row * 32 + col]) =
            cvt8_f32_bf16(&W[(size_t)(bn + row) * K + k0 + col]);
      }
    } else {
#pragma unroll
      for (int t = 0; t < 2; ++t) {
        int chunk = wave * 128 + t * 64 + lane;
        int row = chunk >> 2, col = (chunk & 3) << 3;
        gld16(&W[(size_t)(bn + row) * K + k0 + col], &Bs[row * 32 + col]);
      }
    }
    __syncthreads();
    bf16x8 af[4], bfr[4];
#pragma unroll
    for (int i = 0; i < 4; ++i) {
      af[i]  = *(const bf16x8*)(&As[(wm + i * 16 + l16) * 32 + quad * 8]);
      bfr[i] = *(const bf16x8*)(&Bs[(wn + i * 16 + l16) * 32 + quad * 8]);
    }
#pragma unroll
    for (int mi = 0; mi < 4; ++mi)
#pragma unroll
      for (int ni = 0; ni < 4; ++ni)
        acc[mi][ni] = __builtin_amdgcn_mfma_f32_16x16x32_bf16(
            af[mi], bfr[ni], acc[mi][ni], 0, 0, 0);
  }

#pragma unroll
  for (int mi = 0; mi < 4; ++mi) {
#pragma unroll
    for (int ni = 0; ni < 4; ++ni) {
      int col = bn + wn + ni * 16 + l16;
      float bval = bias[col];
      if (mode == 2) {
        int row0 = bm + wm + mi * 16 + quad * 4;
        int b = row0 >> 11, s = row0 & (S_LEN - 1);
        int h = col >> 7,  d = col & (DH - 1);
        size_t idx0 = (((size_t)(b * NH + h)) * DH + d) * S_LEN + s;
        if constexpr (__is_same(TC, bf16_t)) {
          bf16x4 o4;
#pragma unroll
          for (int r = 0; r < 4; ++r) o4[r] = (bf16_t)((acc[mi][ni][r] + bval) * oscale);
          *(bf16x4*)(&C[idx0]) = o4;
        } else {
#pragma unroll
          for (int r = 0; r < 4; ++r) C[idx0 + r] = (TC)((acc[mi][ni][r] + bval) * oscale);
        }
      } else {
#pragma unroll
        for (int r = 0; r < 4; ++r) {
          int row = bm + wm + mi * 16 + quad * 4 + r;
          float vv = (acc[mi][ni][r] + bval) * oscale;
          size_t idx;
          if (mode == 0) {
            idx = (size_t)row * N + col;
          } else {
            int b = row >> 11, s = row & (S_LEN - 1);
            int h = col >> 7,  d = col & (DH - 1);
            idx = (((size_t)(b * NH + h)) * S_LEN + s) * DH + d;
          }
          C[idx] = (TC)vv;
        }
      }
    }
  }
}

// ---------------- Flash attention, 32x32 swapped structure ----------------
// Q (pre-scaled by 1/sqrt(DH)*log2e): [B*NH,S,DH]  K: [B*NH,S,DH]
// V: [B*NH,DH,S]  O: [B,S,D]
// 4 waves x 32 q-rows = 128 q-rows/block; KVBLK=64; grid 512.
// Swapped QK^T (mfma(K,Q)): lane owns ONE q-row (C/D col=lane&31); softmax is
// in-lane over 32 regs + one shfl_xor(32) to combine the lane/lane+32 halves.
// P -> B-fragments rebuilt in-register via pack + shfl_xor(32) (no LDS Ps).
// K/V double-buffered in LDS via global_load_lds with XOR-swizzled SOURCE
// (rule #21: linear dest + inverse-swz source + swz read). ONE __syncthreads
// per tile; its vmcnt(0) is exactly the drain of the prefetch issued after
// the PREVIOUS barrier (full-tile overlap).
__global__ __launch_bounds__(256, 2)
void attn_fwd(const bf16_t* __restrict__ Q, const bf16_t* __restrict__ Kh,
              const bf16_t* __restrict__ Vt, bf16_t* __restrict__ O,
              const int* __restrict__ causal_p)
{
  __shared__ __align__(16) bf16_t Ks[2][64 * 128];   // [key][dh], src-swizzled
  __shared__ __align__(16) bf16_t Vs[2][128 * 64];   // [dh][key], src-swizzled
  const int tid  = threadIdx.x;
  const int wave = tid >> 6, lane = tid & 63;
  const int l31  = lane & 31, hi = lane >> 5;
  const int id = blockIdx.x;
  const int bh = id & 31;                       // XCD-pinned per head
  const int phase = id >> 5;                    // 0..15
  const int qb = (phase < 8) ? (15 - phase) : (phase - 8);
  const int causal = *causal_p;

  const bf16_t* Qb = Q  + (size_t)bh * S_LEN * DH;
  const bf16_t* Kb = Kh + (size_t)bh * S_LEN * DH;
  const bf16_t* Vb = Vt + (size_t)bh * DH * S_LEN;

  const int qrow   = qb * 128 + wave * 32 + l31;  // this lane's q row
  const int qmin_w = qb * 128 + wave * 32;        // wave-uniform

  // Q fragments (B-operand): lane gives Q[q=l31][kk*16 + hi*8 + j]
  bf16x8 qf[8];
#pragma unroll
  for (int kk = 0; kk < 8; ++kk)
    qf[kk] = *(const bf16x8*)(&Qb[(size_t)qrow * DH + kk * 16 + hi * 8]);

  f32x16 oacc[4] = {};           // O^T: D[dh-block][q], col=lane&31=q
  float mrow = NEG_BIG, lrow = 0.f;

  const int nkb = causal ? (2 * qb + 2) : (S_LEN / 64);

  // stage tile kb_ into buffer buf: 1024 16B-chunks each for K and V.
  // LDS linear; global source pre-swizzled: LDS(r,c) holds G(r, c^(r&7)).
  auto STAGE = [&](int buf, int kb_) {
#pragma unroll
    for (int i = 0; i < 4; ++i) {
      int c = tid + i * 256;
      int kr = c >> 4, kc = c & 15;
      gld16(&Kb[(size_t)(kb_ * 64 + kr) * DH + ((kc ^ (kr & 7)) << 3)],
            &Ks[buf][c << 3]);
      int vr = c >> 3, vc = c & 7;
      gld16(&Vb[(size_t)vr * S_LEN + kb_ * 64 + ((vc ^ (vr & 7)) << 3)],
            &Vs[buf][c << 3]);
    }
  };

  STAGE(0, 0);
  int cur = 0;
  for (int kb = 0; kb < nkb; ++kb) {
    // vmcnt(0)+fence+barrier: buf[cur] (prefetched last iter by ALL waves)
    // is now fully in LDS; buf[cur^1] is free for the next prefetch.
    __syncthreads();
    if (kb + 1 < nkb) STAGE(cur ^ 1, kb + 1);   // in flight over the compute

    if (!causal || (kb * 64 <= qmin_w + 31)) {  // wave-uniform tail skip
      const bf16_t* ks = &Ks[cur][0];
      const bf16_t* vs = &Vs[cur][0];

      // ---- S^T = K Q^T : D[key][q], 64 keys = 2 key-blocks x 16 regs ----
      f32x16 sc[2] = {};
#pragma unroll
      for (int kk = 0; kk < 8; ++kk) {
        int ch = ((kk << 1) | hi) ^ (l31 & 7);
        bf16x8 kf0 = *(const bf16x8*)(&ks[(l31) * 128 + ch * 8]);
        bf16x8 kf1 = *(const bf16x8*)(&ks[(32 + l31) * 128 + ch * 8]);
        sc[0] = __builtin_amdgcn_mfma_f32_32x32x16_bf16(kf0, qf[kk], sc[0], 0, 0, 0);
        sc[1] = __builtin_amdgcn_mfma_f32_32x32x16_bf16(kf1, qf[kk], sc[1], 0, 0, 0);
      }

      // ---- causal mask (boundary tiles only; per-lane q, per-reg key) ----
      // C/D row formula (m74/m101): row32 = (r&3) + 8*(r>>2) + 4*hi
      if (causal && (kb * 64 + 63 > qmin_w)) {
#pragma unroll
        for (int kblk = 0; kblk < 2; ++kblk)
#pragma unroll
          for (int r = 0; r < 16; ++r) {
            int key = kb * 64 + kblk * 32 + (r & 3) + 8 * (r >> 2) + 4 * hi;
            if (key > qrow) sc[kblk][r] = NEG_BIG;
          }
      }

      // ---- online softmax: in-lane over 32 regs + one shfl_xor(32) ----
      float pm = sc[0][0];
#pragma unroll
      for (int r = 1; r < 16; ++r) pm = fmaxf(pm, sc[0][r]);
#pragma unroll
      for (int r = 0; r < 16; ++r) pm = fmaxf(pm, sc[1][r]);
      pm = fmaxf(pm, __shfl_xor(pm, 32));
      float mnew  = fmaxf(mrow, pm);
      float alpha = exp2fast(mrow - mnew);
      mrow = mnew;
      float rs = 0.f;
#pragma unroll
      for (int kblk = 0; kblk < 2; ++kblk)
#pragma unroll
        for (int r = 0; r < 16; ++r) {
          float e = exp2fast(sc[kblk][r] - mnew);
          sc[kblk][r] = e;
          rs += e;
        }
      rs += __shfl_xor(rs, 32);
      lrow = lrow * alpha + rs;
#pragma unroll
      for (int d = 0; d < 4; ++d) oacc[d] *= alpha;

      // ---- P -> bf16 B-fragments in-register (pack + shfl_xor(32)) ----
      u32x4 pw[2][2];
#pragma unroll
      for (int kblk = 0; kblk < 2; ++kblk)
#pragma unroll
        for (int kc = 0; kc < 2; ++kc) {
          int b0 = kc * 8;
          u32 pa = pack_bf16(sc[kblk][b0 + 0], sc[kblk][b0 + 1]);
          u32 pc = pack_bf16(sc[kblk][b0 + 2], sc[kblk][b0 + 3]);
          u32 pb = pack_bf16(sc[kblk][b0 + 4], sc[kblk][b0 + 5]);
          u32 pd = pack_bf16(sc[kblk][b0 + 6], sc[kblk][b0 + 7]);
          u32 qa = (u32)__shfl_xor((int)pa, 32);
          u32 qb_ = (u32)__shfl_xor((int)pb, 32);
          u32 qc = (u32)__shfl_xor((int)pc, 32);
          u32 qd = (u32)__shfl_xor((int)pd, 32);
          u32x4 w;
          w[0] = hi ? qb_ : pa;
          w[1] = hi ? qd  : pc;
          w[2] = hi ? pb  : qa;
          w[3] = hi ? pd  : qc;
          pw[kblk][kc] = w;
        }

      // ---- O^T += V^T P : A = V^T rows=dh (from Vs), B = P frags ----
#pragma unroll
      for (int d = 0; d < 4; ++d) {
        int vrow = d * 32 + l31;
#pragma unroll
        for (int kblk = 0; kblk < 2; ++kblk)
#pragma unroll
          for (int kc = 0; kc < 2; ++kc) {
            bf16x8 vf = *(const bf16x8*)(
                &vs[vrow * 64 + ((((kblk << 2) | (kc << 1) | hi)) ^ (l31 & 7)) * 8]);
            bf16x8 pf = __builtin_bit_cast(bf16x8, pw[kblk][kc]);
            oacc[d] = __builtin_amdgcn_mfma_f32_32x32x16_bf16(vf, pf, oacc[d], 0, 0, 0);
          }
      }
    }
    cur ^= 1;
  }

  // ---- epilogue: O[q][dh]; dh = d*32 + g*8 + hi*4 + j (8B packed stores) --
  const int b = bh >> 4, h = bh & 15;
  float linv = 1.0f / fmaxf(lrow, 1e-20f);
  bf16_t* Ob = O + ((size_t)(b * S_LEN + qrow)) * DMODEL + h * DH;
#pragma unroll
  for (int d = 0; d < 4; ++d)
#pragma unroll
    for (int g = 0; g < 4; ++g) {
      bf16x4 o4;
#pragma unroll
      for (int j = 0; j < 4; ++j) o4[j] = (bf16_t)(oacc[d][g * 4 + j] * linv);
      *(bf16x4*)(&Ob[d * 32 + g * 8 + hi * 4]) = o4;
    }
}

extern "C" void kernel_launch(void* const* d_in, const int* in_sizes, int n_in,
                              void* d_out, int out_size, void* d_ws, size_t ws_size,
                              hipStream_t stream) {
  const float* q  = (const float*)d_in[0];
  const float* k  = (const float*)d_in[1];
  const float* v  = (const float*)d_in[2];
  const float* Wq = (const float*)d_in[3];
  const float* bq = (const float*)d_in[4];
  const float* Wk = (const float*)d_in[5];
  const float* bk = (const float*)d_in[6];
  const float* Wv = (const float*)d_in[7];
  const float* bv = (const float*)d_in[8];
  const float* Wo = (const float*)d_in[9];
  const float* bo = (const float*)d_in[10];
  const int*   cm = (const int*)d_in[11];

  float* out = (float*)d_out;
  const size_t NA = (size_t)MROWS * DMODEL;     // 8,388,608
  const size_t NW = (size_t)DMODEL * DMODEL;    // 4,194,304
  // 1/sqrt(128) * log2(e): scores land in exp2 domain (v_exp_f32 direct)
  const float qscale = 0.08838834764831845f * 1.4426950408889634f;

  bf16_t* p0 = (bf16_t*)d_ws;
  const size_t needA = (4 * NW + 7 * NA) * sizeof(bf16_t);  // ~151 MB
  const size_t needB = (4 * NW + 4 * NA) * sizeof(bf16_t);  // ~101 MB

  dim3 gg(MROWS / 128, DMODEL / 128), bb(256);
  dim3 g2(512);
  dim3 cgW(2048), cgA(4096);
  dim3 ga(512);
  bf16_t *Qh, *Kh, *Vh, *Ao;

  if (ws_size >= needA) {
    bf16_t *Wqb = p0, *Wkb = p0 + NW, *Wvb = p0 + 2 * NW, *Wob = p0 + 3 * NW;
    bf16_t *qb2 = p0 + 4 * NW, *kb2 = qb2 + NA, *vb2 = kb2 + NA;
    Qh = vb2 + NA; Kh = Qh + NA; Vh = Kh + NA; Ao = Vh + NA;
    cvt_bf16<<<cgW, bb, 0, stream>>>(Wq, Wqb, (int)(NW / 8));
    cvt_bf16<<<cgW, bb, 0, stream>>>(Wk, Wkb, (int)(NW / 8));
    cvt_bf16<<<cgW, bb, 0, stream>>>(Wv, Wvb, (int)(NW / 8));
    cvt_bf16<<<cgW, bb, 0, stream>>>(Wo, Wob, (int)(NW / 8));
    cvt_bf16<<<cgA, bb, 0, stream>>>(q, qb2, (int)(NA / 8));
    cvt_bf16<<<cgA, bb, 0, stream>>>(k, kb2, (int)(NA / 8));
    cvt_bf16<<<cgA, bb, 0, stream>>>(v, vb2, (int)(NA / 8));
    gemm_bt2<bf16_t><<<g2, bb, 0, stream>>>(qb2, Wqb, bq, Qh, 1, qscale);
    gemm_bt2<bf16_t><<<g2, bb, 0, stream>>>(kb2, Wkb, bk, Kh, 1, 1.0f);
    gemm_bt2<bf16_t><<<g2, bb, 0, stream>>>(vb2, Wvb, bv, Vh, 2, 1.0f);
    attn_fwd<<<ga, bb, 0, stream>>>(Qh, Kh, Vh, Ao, cm);
    gemm_bt2<float><<<g2, bb, 0, stream>>>(Ao, Wob, bo, out, 0, 1.0f);
  } else if (ws_size >= needB) {
    bf16_t *Wqb = p0, *Wkb = p0 + NW, *Wvb = p0 + 2 * NW, *Wob = p0 + 3 * NW;
    Qh = p0 + 4 * NW; Kh = Qh + NA; Vh = Kh + NA; Ao = Vh + NA;
    cvt_bf16<<<cgW, bb, 0, stream>>>(Wq, Wqb, (int)(NW / 8));
    cvt_bf16<<<cgW, bb, 0, stream>>>(Wk, Wkb, (int)(NW / 8));
    cvt_bf16<<<cgW, bb, 0, stream>>>(Wv, Wvb, (int)(NW / 8));
    cvt_bf16<<<cgW, bb, 0, stream>>>(Wo, Wob, (int)(NW / 8));
    gemm_bt<float, bf16_t, bf16_t><<<gg, bb, 0, stream>>>(q, Wqb, bq, Qh, 1, qscale);
    gemm_bt<float, bf16_t, bf16_t><<<gg, bb, 0, stream>>>(k, Wkb, bk, Kh, 1, 1.0f);
    gemm_bt<float, bf16_t, bf16_t><<<gg, bb, 0, stream>>>(v, Wvb, bv, Vh, 2, 1.0f);
    attn_fwd<<<ga, bb, 0, stream>>>(Qh, Kh, Vh, Ao, cm);
    gemm_bt2<float><<<g2, bb, 0, stream>>>(Ao, Wob, bo, out, 0, 1.0f);
  } else {
    Qh = p0; Kh = Qh + NA; Vh = Kh + NA; Ao = Vh + NA;
    gemm_bt<float, float, bf16_t><<<gg, bb, 0, stream>>>(q, Wq, bq, Qh, 1, qscale);
    gemm_bt<float, float, bf16_t><<<gg, bb, 0, stream>>>(k, Wk, bk, Kh, 1, 1.0f);
    gemm_bt<float, float, bf16_t><<<gg, bb, 0, stream>>>(v, Wv, bv, Vh, 2, 1.0f);
    attn_fwd<<<ga, bb, 0, stream>>>(Qh, Kh, Vh, Ao, cm);
    gemm_bt<bf16_t, float, float><<<gg, bb, 0, stream>>>(Ao, Wo, bo, out, 0, 1.0f);
  }
}

// Round 5
// 472.891 us; speedup vs baseline: 1.0396x; 1.0396x over previous
//
#include <hip/hip_runtime.h>
#include <hip/hip_bf16.h>

typedef __bf16 bf16_t;
typedef bf16_t bf16x8 __attribute__((ext_vector_type(8)));
typedef bf16_t bf16x4 __attribute__((ext_vector_type(4)));
typedef float  f32x4  __attribute__((ext_vector_type(4)));
typedef float  f32x16 __attribute__((ext_vector_type(16)));
typedef unsigned int u32;
typedef u32 u32x4 __attribute__((ext_vector_type(4)));

#define S_LEN  2048
#define DMODEL 2048
#define NH     16
#define DH     128
#define BATCH  2
#define MROWS  (BATCH * S_LEN)   // 4096

#define NEG_BIG (-1.0e30f)

__device__ __forceinline__ bf16x8 cvt8_f32_bf16(const float* __restrict__ p) {
  float4 f0 = *(const float4*)(p);
  float4 f1 = *(const float4*)(p + 4);
  bf16x8 r;
  r[0] = (bf16_t)f0.x; r[1] = (bf16_t)f0.y; r[2] = (bf16_t)f0.z; r[3] = (bf16_t)f0.w;
  r[4] = (bf16_t)f1.x; r[5] = (bf16_t)f1.y; r[6] = (bf16_t)f1.z; r[7] = (bf16_t)f1.w;
  return r;
}

// async global(16B/lane) -> LDS. Dest = wave-uniform base + lane*16 (m97/m104).
__device__ __forceinline__ void gld16(const void* g, void* l) {
  __builtin_amdgcn_global_load_lds(
      (const __attribute__((address_space(1))) void*)g,
      (__attribute__((address_space(3))) void*)l, 16, 0, 0);
}

__device__ __forceinline__ float exp2fast(float x) {
#if __has_builtin(__builtin_amdgcn_exp2f)
  return __builtin_amdgcn_exp2f(x);
#else
  return __expf(x * 0.6931471805599453f);
#endif
}

// pack two f32 -> one u32 of 2 bf16 (lo in [15:0], hi in [31:16]).
__device__ __forceinline__ u32 pack_bf16(float lo, float hi) {
  union { bf16_t h[2]; u32 w; } u;
  u.h[0] = (bf16_t)lo; u.h[1] = (bf16_t)hi;
  return u.w;
}

// ---------------- fp32 -> bf16 conversion (fused launches) ----------------
// 4 weight matrices -> 4 contiguous NW-regions at dst. Grid = 4*blocksPer.
__global__ __launch_bounds__(256)
void cvt_bf16_w4(const float* __restrict__ a, const float* __restrict__ b,
                 const float* __restrict__ c, const float* __restrict__ d,
                 bf16_t* __restrict__ o, int blocksPer) {
  int which = blockIdx.x / blocksPer;               // block-uniform
  int j = (blockIdx.x - which * blocksPer) * 256 + threadIdx.x;
  const float* s = (which == 0) ? a : (which == 1) ? b : (which == 2) ? c : d;
  bf16_t* dst = o + (size_t)which * ((size_t)blocksPer * 256 * 8);
  *(bf16x8*)(&dst[(size_t)j * 8]) = cvt8_f32_bf16(&s[(size_t)j * 8]);
}

// q,k,v -> 3 contiguous NA-regions at dst. Grid = 3*blocksPer.
__global__ __launch_bounds__(256)
void cvt_bf16_a3(const float* __restrict__ a, const float* __restrict__ b,
                 const float* __restrict__ c, bf16_t* __restrict__ o, int blocksPer) {
  int which = blockIdx.x / blocksPer;
  int j = (blockIdx.x - which * blocksPer) * 256 + threadIdx.x;
  const float* s = (which == 0) ? a : (which == 1) ? b : c;
  bf16_t* dst = o + (size_t)which * ((size_t)blocksPer * 256 * 8);
  *(bf16x8*)(&dst[(size_t)j * 8]) = cvt8_f32_bf16(&s[(size_t)j * 8]);
}

// ---------------- GEMM (v1, known-good): C = (A @ W^T + bias) * oscale -----
// m97 structure: BK=32, unpadded LDS, global_load_lds for bf16 operands.
// mode 0: C[row*N+col]; 1: [B,H,S,DH]; 2: [B,H,DH,S] (V transposed)
template <typename TA, typename TW, typename TC>
__global__ __launch_bounds__(256)
void gemm_bt(const TA* __restrict__ A, const TW* __restrict__ W,
             const float* __restrict__ bias, TC* __restrict__ C,
             int mode, float oscale)
{
  constexpr int K = DMODEL, N = DMODEL;
  __shared__ __align__(16) bf16_t As[128 * 32];
  __shared__ __align__(16) bf16_t Bs[128 * 32];
  const int tid  = threadIdx.x;
  const int wave = tid >> 6, lane = tid & 63;
  const int quad = lane >> 4, l16 = lane & 15;
  const int bm = blockIdx.x * 128, bn = blockIdx.y * 128;
  const int wm = (wave >> 1) * 64, wn = (wave & 1) * 64;

  f32x4 acc[4][4] = {};

  for (int k0 = 0; k0 < K; k0 += 32) {
    __syncthreads();
    if constexpr (__is_same(TA, float)) {
#pragma unroll
      for (int i = 0; i < 2; ++i) {
        int c = tid + i * 256, row = c >> 2, col = (c & 3) << 3;
        *(bf16x8*)(&As[row * 32 + col]) =
            cvt8_f32_bf16(&A[(size_t)(bm + row) * K + k0 + col]);
      }
    } else {
#pragma unroll
      for (int t = 0; t < 2; ++t) {
        int chunk = wave * 128 + t * 64 + lane;
        int row = chunk >> 2, col = (chunk & 3) << 3;
        gld16(&A[(size_t)(bm + row) * K + k0 + col], &As[row * 32 + col]);
      }
    }
    if constexpr (__is_same(TW, float)) {
#pragma unroll
      for (int i = 0; i < 2; ++i) {
        int c = tid + i * 256, row = c >> 2, col = (c & 3) << 3;
        *(bf16x8*)(&Bs[row * 32 + col]) =
            cvt8_f32_bf16(&W[(size_t)(bn + row) * K + k0 + col]);
      }
    } else {
#pragma unroll
      for (int t = 0; t < 2; ++t) {
        int chunk = wave * 128 + t * 64 + lane;
        int row = chunk >> 2, col = (chunk & 3) << 3;
        gld16(&W[(size_t)(bn + row) * K + k0 + col], &Bs[row * 32 + col]);
      }
    }
    __syncthreads();
    bf16x8 af[4], bfr[4];
#pragma unroll
    for (int i = 0; i < 4; ++i) {
      af[i]  = *(const bf16x8*)(&As[(wm + i * 16 + l16) * 32 + quad * 8]);
      bfr[i] = *(const bf16x8*)(&Bs[(wn + i * 16 + l16) * 32 + quad * 8]);
    }
#pragma unroll
    for (int mi = 0; mi < 4; ++mi)
#pragma unroll
      for (int ni = 0; ni < 4; ++ni)
        acc[mi][ni] = __builtin_amdgcn_mfma_f32_16x16x32_bf16(
            af[mi], bfr[ni], acc[mi][ni], 0, 0, 0);
  }

#pragma unroll
  for (int mi = 0; mi < 4; ++mi) {
#pragma unroll
    for (int ni = 0; ni < 4; ++ni) {
      int col = bn + wn + ni * 16 + l16;
      float bval = bias[col];
      if (mode == 2) {
        int row0 = bm + wm + mi * 16 + quad * 4;
        int b = row0 >> 11, s = row0 & (S_LEN - 1);
        int h = col >> 7,  d = col & (DH - 1);
        size_t idx0 = (((size_t)(b * NH + h)) * DH + d) * S_LEN + s;
        if constexpr (__is_same(TC, bf16_t)) {
          bf16x4 o4;
#pragma unroll
          for (int r = 0; r < 4; ++r) o4[r] = (bf16_t)((acc[mi][ni][r] + bval) * oscale);
          *(bf16x4*)(&C[idx0]) = o4;
        } else {
#pragma unroll
          for (int r = 0; r < 4; ++r) C[idx0 + r] = (TC)((acc[mi][ni][r] + bval) * oscale);
        }
      } else {
#pragma unroll
        for (int r = 0; r < 4; ++r) {
          int row = bm + wm + mi * 16 + quad * 4 + r;
          float vv = (acc[mi][ni][r] + bval) * oscale;
          size_t idx;
          if (mode == 0) {
            idx = (size_t)row * N + col;
          } else {
            int b = row >> 11, s = row & (S_LEN - 1);
            int h = col >> 7,  d = col & (DH - 1);
            idx = (((size_t)(b * NH + h)) * S_LEN + s) * DH + d;
          }
          C[idx] = (TC)vv;
        }
      }
    }
  }
}

// ---------------- Flash attention, 32x32 swapped structure ----------------
// Q (pre-scaled by 1/sqrt(DH)*log2e): [B*NH,S,DH]  K: [B*NH,S,DH]
// V: [B*NH,DH,S]  O: [B,S,D]
// 4 waves x 32 q-rows = 128 q-rows/block; KVBLK=64; grid 512.
// Swapped QK^T (mfma(K,Q)): lane owns ONE q-row; softmax in-lane + shfl(32).
// V is NOT LDS-staged (Common-mistake #7): [B,H,DH,S] layout IS the PV
// A-fragment layout, so V frags load straight global->reg at tile-top; the
// 16KB tile is L1/L2-served (XCD-pinned head) and QK+softmax hides latency.
// K double-buffered in LDS via global_load_lds, XOR-swizzled source+read.
// ONE __syncthreads per tile; next K-tile's gld16 fly across the compute.
__global__ __launch_bounds__(256, 2)
void attn_fwd(const bf16_t* __restrict__ Q, const bf16_t* __restrict__ Kh,
              const bf16_t* __restrict__ Vt, bf16_t* __restrict__ O,
              const int* __restrict__ causal_p)
{
  __shared__ __align__(16) bf16_t Ks[2][64 * 128];   // [key][dh], src-swizzled
  const int tid  = threadIdx.x;
  const int wave = tid >> 6, lane = tid & 63;
  const int l31  = lane & 31, hi = lane >> 5;
  const int id = blockIdx.x;
  const int bh = id & 31;                       // XCD-pinned per head
  const int phase = id >> 5;                    // 0..15
  const int qb = (phase < 8) ? (15 - phase) : (phase - 8);
  const int causal = *causal_p;

  const bf16_t* Qb = Q  + (size_t)bh * S_LEN * DH;
  const bf16_t* Kb = Kh + (size_t)bh * S_LEN * DH;
  const bf16_t* Vb = Vt + (size_t)bh * DH * S_LEN;

  const int qrow   = qb * 128 + wave * 32 + l31;  // this lane's q row
  const int qmin_w = qb * 128 + wave * 32;        // wave-uniform

  // Q fragments (B-operand): lane gives Q[q=l31][kk*16 + hi*8 + j]
  bf16x8 qf[8];
#pragma unroll
  for (int kk = 0; kk < 8; ++kk)
    qf[kk] = *(const bf16x8*)(&Qb[(size_t)qrow * DH + kk * 16 + hi * 8]);

  f32x16 oacc[4] = {};           // O^T: D[dh-block][q], col=lane&31=q
  float mrow = NEG_BIG, lrow = 0.f;

  const int nkb = causal ? (2 * qb + 2) : (S_LEN / 64);

  // stage K tile kb_ into buffer buf: 1024 16B-chunks.
  // LDS linear; global source pre-swizzled: LDS(r,c) holds G(r, c^(r&7)).
  auto STAGE = [&](int buf, int kb_) {
#pragma unroll
    for (int i = 0; i < 4; ++i) {
      int c = tid + i * 256;
      int kr = c >> 4, kc = c & 15;
      gld16(&Kb[(size_t)(kb_ * 64 + kr) * DH + ((kc ^ (kr & 7)) << 3)],
            &Ks[buf][c << 3]);
    }
  };

  STAGE(0, 0);
  int cur = 0;
  for (int kb = 0; kb < nkb; ++kb) {
    // vmcnt(0)+fence+barrier: buf[cur] (prefetched last iter by ALL waves)
    // is now fully in LDS; buf[cur^1] is free for the next prefetch.
    __syncthreads();
    if (kb + 1 < nkb) STAGE(cur ^ 1, kb + 1);   // in flight over the compute

    if (!causal || (kb * 64 <= qmin_w + 31)) {  // wave-uniform tail skip
      const bf16_t* ks = &Ks[cur][0];

      // ---- V fragments: direct global->reg, issued early (latency hides
      // under QK^T + softmax). vfr[d][t]: V[dh=d*32+l31][kb*64+t*16+hi*8..7]
      bf16x8 vfr[4][4];
#pragma unroll
      for (int d = 0; d < 4; ++d)
#pragma unroll
        for (int t = 0; t < 4; ++t)
          vfr[d][t] = *(const bf16x8*)(
              &Vb[(size_t)(d * 32 + l31) * S_LEN + kb * 64 + t * 16 + hi * 8]);

      // ---- S^T = K Q^T : D[key][q], 64 keys = 2 key-blocks x 16 regs ----
      f32x16 sc[2] = {};
      __builtin_amdgcn_s_setprio(1);
#pragma unroll
      for (int kk = 0; kk < 8; ++kk) {
        int ch = ((kk << 1) | hi) ^ (l31 & 7);
        bf16x8 kf0 = *(const bf16x8*)(&ks[(l31) * 128 + ch * 8]);
        bf16x8 kf1 = *(const bf16x8*)(&ks[(32 + l31) * 128 + ch * 8]);
        sc[0] = __builtin_amdgcn_mfma_f32_32x32x16_bf16(kf0, qf[kk], sc[0], 0, 0, 0);
        sc[1] = __builtin_amdgcn_mfma_f32_32x32x16_bf16(kf1, qf[kk], sc[1], 0, 0, 0);
      }
      __builtin_amdgcn_s_setprio(0);

      // ---- causal mask (boundary tiles only; per-lane q, per-reg key) ----
      // C/D row formula (m74/m101): row32 = (r&3) + 8*(r>>2) + 4*hi
      if (causal && (kb * 64 + 63 > qmin_w)) {
#pragma unroll
        for (int kblk = 0; kblk < 2; ++kblk)
#pragma unroll
          for (int r = 0; r < 16; ++r) {
            int key = kb * 64 + kblk * 32 + (r & 3) + 8 * (r >> 2) + 4 * hi;
            if (key > qrow) sc[kblk][r] = NEG_BIG;
          }
      }

      // ---- online softmax: in-lane over 32 regs + one shfl_xor(32) ----
      float pm = sc[0][0];
#pragma unroll
      for (int r = 1; r < 16; ++r) pm = fmaxf(pm, sc[0][r]);
#pragma unroll
      for (int r = 0; r < 16; ++r) pm = fmaxf(pm, sc[1][r]);
      pm = fmaxf(pm, __shfl_xor(pm, 32));
      float mnew  = fmaxf(mrow, pm);
      float alpha = exp2fast(mrow - mnew);
      mrow = mnew;
      float rs = 0.f;
#pragma unroll
      for (int kblk = 0; kblk < 2; ++kblk)
#pragma unroll
        for (int r = 0; r < 16; ++r) {
          float e = exp2fast(sc[kblk][r] - mnew);
          sc[kblk][r] = e;
          rs += e;
        }
      rs += __shfl_xor(rs, 32);
      lrow = lrow * alpha + rs;
#pragma unroll
      for (int d = 0; d < 4; ++d) oacc[d] *= alpha;

      // ---- P -> bf16 B-fragments in-register (pack + shfl_xor(32)) ----
      u32x4 pw[2][2];
#pragma unroll
      for (int kblk = 0; kblk < 2; ++kblk)
#pragma unroll
        for (int kc = 0; kc < 2; ++kc) {
          int b0 = kc * 8;
          u32 pa = pack_bf16(sc[kblk][b0 + 0], sc[kblk][b0 + 1]);
          u32 pc = pack_bf16(sc[kblk][b0 + 2], sc[kblk][b0 + 3]);
          u32 pb = pack_bf16(sc[kblk][b0 + 4], sc[kblk][b0 + 5]);
          u32 pd = pack_bf16(sc[kblk][b0 + 6], sc[kblk][b0 + 7]);
          u32 qa = (u32)__shfl_xor((int)pa, 32);
          u32 qb_ = (u32)__shfl_xor((int)pb, 32);
          u32 qc = (u32)__shfl_xor((int)pc, 32);
          u32 qd = (u32)__shfl_xor((int)pd, 32);
          u32x4 w;
          w[0] = hi ? qb_ : pa;
          w[1] = hi ? qd  : pc;
          w[2] = hi ? pb  : qa;
          w[3] = hi ? pd  : qc;
          pw[kblk][kc] = w;
        }

      // ---- O^T += V^T P : A = V frags (regs), B = P frags ----
      __builtin_amdgcn_s_setprio(1);
#pragma unroll
      for (int d = 0; d < 4; ++d)
#pragma unroll
        for (int kblk = 0; kblk < 2; ++kblk)
#pragma unroll
          for (int kc = 0; kc < 2; ++kc) {
            bf16x8 pf = __builtin_bit_cast(bf16x8, pw[kblk][kc]);
            oacc[d] = __builtin_amdgcn_mfma_f32_32x32x16_bf16(
                vfr[d][kblk * 2 + kc], pf, oacc[d], 0, 0, 0);
          }
      __builtin_amdgcn_s_setprio(0);
    }
    cur ^= 1;
  }

  // ---- epilogue: O[q][dh]; dh = d*32 + g*8 + hi*4 + j (8B packed stores) --
  const int b = bh >> 4, h = bh & 15;
  float linv = 1.0f / fmaxf(lrow, 1e-20f);
  bf16_t* Ob = O + ((size_t)(b * S_LEN + qrow)) * DMODEL + h * DH;
#pragma unroll
  for (int d = 0; d < 4; ++d)
#pragma unroll
    for (int g = 0; g < 4; ++g) {
      bf16x4 o4;
#pragma unroll
      for (int j = 0; j < 4; ++j) o4[j] = (bf16_t)(oacc[d][g * 4 + j] * linv);
      *(bf16x4*)(&Ob[d * 32 + g * 8 + hi * 4]) = o4;
    }
}

extern "C" void kernel_launch(void* const* d_in, const int* in_sizes, int n_in,
                              void* d_out, int out_size, void* d_ws, size_t ws_size,
                              hipStream_t stream) {
  const float* q  = (const float*)d_in[0];
  const float* k  = (const float*)d_in[1];
  const float* v  = (const float*)d_in[2];
  const float* Wq = (const float*)d_in[3];
  const float* bq = (const float*)d_in[4];
  const float* Wk = (const float*)d_in[5];
  const float* bk = (const float*)d_in[6];
  const float* Wv = (const float*)d_in[7];
  const float* bv = (const float*)d_in[8];
  const float* Wo = (const float*)d_in[9];
  const float* bo = (const float*)d_in[10];
  const int*   cm = (const int*)d_in[11];

  float* out = (float*)d_out;
  const size_t NA = (size_t)MROWS * DMODEL;     // 8,388,608
  const size_t NW = (size_t)DMODEL * DMODEL;    // 4,194,304
  // 1/sqrt(128) * log2(e): scores land in exp2 domain (v_exp_f32 direct)
  const float qscale = 0.08838834764831845f * 1.4426950408889634f;

  bf16_t* p0 = (bf16_t*)d_ws;
  const size_t needA = (4 * NW + 7 * NA) * sizeof(bf16_t);  // ~151 MB
  const size_t needB = (4 * NW + 4 * NA) * sizeof(bf16_t);  // ~101 MB

  dim3 gg(MROWS / 128, DMODEL / 128), bb(256);
  dim3 ga(512);
  bf16_t *Qh, *Kh, *Vh, *Ao;

  if (ws_size >= needA) {
    bf16_t *Wqb = p0;                       // 4 contiguous NW regions
    bf16_t *qb2 = p0 + 4 * NW;              // 3 contiguous NA regions
    bf16_t *kb2 = qb2 + NA, *vb2 = kb2 + NA;
    Qh = vb2 + NA; Kh = Qh + NA; Vh = Kh + NA; Ao = Vh + NA;
    cvt_bf16_w4<<<dim3(4 * (int)(NW / 2048)), bb, 0, stream>>>(
        Wq, Wk, Wv, Wo, Wqb, (int)(NW / 2048));
    cvt_bf16_a3<<<dim3(3 * (int)(NA / 2048)), bb, 0, stream>>>(
        q, k, v, qb2, (int)(NA / 2048));
    gemm_bt<bf16_t, bf16_t, bf16_t><<<gg, bb, 0, stream>>>(qb2, Wqb,          bq, Qh, 1, qscale);
    gemm_bt<bf16_t, bf16_t, bf16_t><<<gg, bb, 0, stream>>>(kb2, Wqb + NW,     bk, Kh, 1, 1.0f);
    gemm_bt<bf16_t, bf16_t, bf16_t><<<gg, bb, 0, stream>>>(vb2, Wqb + 2 * NW, bv, Vh, 2, 1.0f);
    attn_fwd<<<ga, bb, 0, stream>>>(Qh, Kh, Vh, Ao, cm);
    gemm_bt<bf16_t, bf16_t, float><<<gg, bb, 0, stream>>>(Ao, Wqb + 3 * NW, bo, out, 0, 1.0f);
  } else if (ws_size >= needB) {
    bf16_t *Wqb = p0;
    Qh = p0 + 4 * NW; Kh = Qh + NA; Vh = Kh + NA; Ao = Vh + NA;
    cvt_bf16_w4<<<dim3(4 * (int)(NW / 2048)), bb, 0, stream>>>(
        Wq, Wk, Wv, Wo, Wqb, (int)(NW / 2048));
    gemm_bt<float, bf16_t, bf16_t><<<gg, bb, 0, stream>>>(q, Wqb,          bq, Qh, 1, qscale);
    gemm_bt<float, bf16_t, bf16_t><<<gg, bb, 0, stream>>>(k, Wqb + NW,     bk, Kh, 1, 1.0f);
    gemm_bt<float, bf16_t, bf16_t><<<gg, bb, 0, stream>>>(v, Wqb + 2 * NW, bv, Vh, 2, 1.0f);
    attn_fwd<<<ga, bb, 0, stream>>>(Qh, Kh, Vh, Ao, cm);
    gemm_bt<bf16_t, bf16_t, float><<<gg, bb, 0, stream>>>(Ao, Wqb + 3 * NW, bo, out, 0, 1.0f);
  } else {
    Qh = p0; Kh = Qh + NA; Vh = Kh + NA; Ao = Vh + NA;
    gemm_bt<float, float, bf16_t><<<gg, bb, 0, stream>>>(q, Wq, bq, Qh, 1, qscale);
    gemm_bt<float, float, bf16_t><<<gg, bb, 0, stream>>>(k, Wk, bk, Kh, 1, 1.0f);
    gemm_bt<float, float, bf16_t><<<gg, bb, 0, stream>>>(v, Wv, bv, Vh, 2, 1.0f);
    attn_fwd<<<ga, bb, 0, stream>>>(Qh, Kh, Vh, Ao, cm);
    gemm_bt<bf16_t, float, float><<<gg, bb, 0, stream>>>(Ao, Wo, bo, out, 0, 1.0f);
  }
}

// Round 6
// 431.370 us; speedup vs baseline: 1.1397x; 1.0963x over previous
//
#include <hip/hip_runtime.h>
#include <hip/hip_bf16.h>

typedef __bf16 bf16_t;
typedef bf16_t bf16x8 __attribute__((ext_vector_type(8)));
typedef bf16_t bf16x4 __attribute__((ext_vector_type(4)));
typedef float  f32x4  __attribute__((ext_vector_type(4)));
typedef float  f32x16 __attribute__((ext_vector_type(16)));
typedef unsigned int u32;
typedef u32 u32x4 __attribute__((ext_vector_type(4)));

#define S_LEN  2048
#define DMODEL 2048
#define NH     16
#define DH     128
#define BATCH  2
#define MROWS  (BATCH * S_LEN)   // 4096

#define NEG_BIG (-1.0e30f)

__device__ __forceinline__ bf16x8 cvt8_f32_bf16(const float* __restrict__ p) {
  float4 f0 = *(const float4*)(p);
  float4 f1 = *(const float4*)(p + 4);
  bf16x8 r;
  r[0] = (bf16_t)f0.x; r[1] = (bf16_t)f0.y; r[2] = (bf16_t)f0.z; r[3] = (bf16_t)f0.w;
  r[4] = (bf16_t)f1.x; r[5] = (bf16_t)f1.y; r[6] = (bf16_t)f1.z; r[7] = (bf16_t)f1.w;
  return r;
}

// async global(16B/lane) -> LDS. Dest = wave-uniform base + lane*16 (m97/m104).
__device__ __forceinline__ void gld16(const void* g, void* l) {
  __builtin_amdgcn_global_load_lds(
      (const __attribute__((address_space(1))) void*)g,
      (__attribute__((address_space(3))) void*)l, 16, 0, 0);
}

__device__ __forceinline__ float exp2fast(float x) {
#if __has_builtin(__builtin_amdgcn_exp2f)
  return __builtin_amdgcn_exp2f(x);
#else
  return __expf(x * 0.6931471805599453f);
#endif
}

// pack two f32 -> one u32 of 2 bf16 (lo in [15:0], hi in [31:16]).
__device__ __forceinline__ u32 pack_bf16(float lo, float hi) {
  union { bf16_t h[2]; u32 w; } u;
  u.h[0] = (bf16_t)lo; u.h[1] = (bf16_t)hi;
  return u.w;
}

// ---------------- fp32 -> bf16 conversion (fused launches) ----------------
// 4 weight matrices -> 4 contiguous NW-regions at dst. Grid = 4*blocksPer.
__global__ __launch_bounds__(256)
void cvt_bf16_w4(const float* __restrict__ a, const float* __restrict__ b,
                 const float* __restrict__ c, const float* __restrict__ d,
                 bf16_t* __restrict__ o, int blocksPer) {
  int which = blockIdx.x / blocksPer;               // block-uniform
  int j = (blockIdx.x - which * blocksPer) * 256 + threadIdx.x;
  const float* s = (which == 0) ? a : (which == 1) ? b : (which == 2) ? c : d;
  bf16_t* dst = o + (size_t)which * ((size_t)blocksPer * 256 * 8);
  *(bf16x8*)(&dst[(size_t)j * 8]) = cvt8_f32_bf16(&s[(size_t)j * 8]);
}

// q,k,v -> 3 contiguous NA-regions at dst. Grid = 3*blocksPer.
__global__ __launch_bounds__(256)
void cvt_bf16_a3(const float* __restrict__ a, const float* __restrict__ b,
                 const float* __restrict__ c, bf16_t* __restrict__ o, int blocksPer) {
  int which = blockIdx.x / blocksPer;
  int j = (blockIdx.x - which * blocksPer) * 256 + threadIdx.x;
  const float* s = (which == 0) ? a : (which == 1) ? b : c;
  bf16_t* dst = o + (size_t)which * ((size_t)blocksPer * 256 * 8);
  *(bf16x8*)(&dst[(size_t)j * 8]) = cvt8_f32_bf16(&s[(size_t)j * 8]);
}

// ------ Batched QKV GEMM: z in {0,1,2} -> (Q,K,V) projection -----------
// Identical inner loop to gemm_bt (m97 structure, known-good). Batching the 3
// independent GEMMs into one 1536-block launch raises co-residency from
// 2-3 to VGPR-cap (~3-5) blocks/CU, hiding the per-K-step barrier drain via
// cross-block wave overlap (m114), and saves 2 launch gaps.
// A/W/C regions are contiguous per z; bias/mode/oscale z-selected (uniform).
__global__ __launch_bounds__(256)
void qkv_gemm(const bf16_t* __restrict__ Abase, const bf16_t* __restrict__ Wbase,
              const float* __restrict__ bq, const float* __restrict__ bk,
              const float* __restrict__ bv, bf16_t* __restrict__ Cbase,
              float qscale0)
{
  constexpr int K = DMODEL;
  const int z = blockIdx.z;
  const size_t NA = (size_t)MROWS * DMODEL, NW = (size_t)DMODEL * DMODEL;
  const bf16_t* A = Abase + (size_t)z * NA;
  const bf16_t* W = Wbase + (size_t)z * NW;
  bf16_t*       C = Cbase + (size_t)z * NA;
  const float* bias = (z == 0) ? bq : (z == 1) ? bk : bv;
  const int   mode   = (z == 2) ? 2 : 1;
  const float oscale = (z == 0) ? qscale0 : 1.0f;

  __shared__ __align__(16) bf16_t As[128 * 32];
  __shared__ __align__(16) bf16_t Bs[128 * 32];
  const int tid  = threadIdx.x;
  const int wave = tid >> 6, lane = tid & 63;
  const int quad = lane >> 4, l16 = lane & 15;
  const int bm = blockIdx.x * 128, bn = blockIdx.y * 128;
  const int wm = (wave >> 1) * 64, wn = (wave & 1) * 64;

  f32x4 acc[4][4] = {};

  for (int k0 = 0; k0 < K; k0 += 32) {
    __syncthreads();
#pragma unroll
    for (int t = 0; t < 2; ++t) {
      int chunk = wave * 128 + t * 64 + lane;
      int row = chunk >> 2, col = (chunk & 3) << 3;
      gld16(&A[(size_t)(bm + row) * K + k0 + col], &As[row * 32 + col]);
    }
#pragma unroll
    for (int t = 0; t < 2; ++t) {
      int chunk = wave * 128 + t * 64 + lane;
      int row = chunk >> 2, col = (chunk & 3) << 3;
      gld16(&W[(size_t)(bn + row) * K + k0 + col], &Bs[row * 32 + col]);
    }
    __syncthreads();
    bf16x8 af[4], bfr[4];
#pragma unroll
    for (int i = 0; i < 4; ++i) {
      af[i]  = *(const bf16x8*)(&As[(wm + i * 16 + l16) * 32 + quad * 8]);
      bfr[i] = *(const bf16x8*)(&Bs[(wn + i * 16 + l16) * 32 + quad * 8]);
    }
#pragma unroll
    for (int mi = 0; mi < 4; ++mi)
#pragma unroll
      for (int ni = 0; ni < 4; ++ni)
        acc[mi][ni] = __builtin_amdgcn_mfma_f32_16x16x32_bf16(
            af[mi], bfr[ni], acc[mi][ni], 0, 0, 0);
  }

#pragma unroll
  for (int mi = 0; mi < 4; ++mi) {
#pragma unroll
    for (int ni = 0; ni < 4; ++ni) {
      int col = bn + wn + ni * 16 + l16;
      float bval = bias[col];
      if (mode == 2) {
        int row0 = bm + wm + mi * 16 + quad * 4;
        int b = row0 >> 11, s = row0 & (S_LEN - 1);
        int h = col >> 7,  d = col & (DH - 1);
        size_t idx0 = (((size_t)(b * NH + h)) * DH + d) * S_LEN + s;
        bf16x4 o4;
#pragma unroll
        for (int r = 0; r < 4; ++r) o4[r] = (bf16_t)((acc[mi][ni][r] + bval) * oscale);
        *(bf16x4*)(&C[idx0]) = o4;
      } else {
#pragma unroll
        for (int r = 0; r < 4; ++r) {
          int row = bm + wm + mi * 16 + quad * 4 + r;
          int b = row >> 11, s = row & (S_LEN - 1);
          int h = col >> 7,  d = col & (DH - 1);
          size_t idx = (((size_t)(b * NH + h)) * S_LEN + s) * DH + d;
          C[idx] = (bf16_t)((acc[mi][ni][r] + bval) * oscale);
        }
      }
    }
  }
}

// ---------------- GEMM (v1, known-good): C = (A @ W^T + bias) * oscale -----
// m97 structure: BK=32, unpadded LDS, global_load_lds for bf16 operands.
// mode 0: C[row*N+col]; 1: [B,H,S,DH]; 2: [B,H,DH,S] (V transposed)
template <typename TA, typename TW, typename TC>
__global__ __launch_bounds__(256)
void gemm_bt(const TA* __restrict__ A, const TW* __restrict__ W,
             const float* __restrict__ bias, TC* __restrict__ C,
             int mode, float oscale)
{
  constexpr int K = DMODEL, N = DMODEL;
  __shared__ __align__(16) bf16_t As[128 * 32];
  __shared__ __align__(16) bf16_t Bs[128 * 32];
  const int tid  = threadIdx.x;
  const int wave = tid >> 6, lane = tid & 63;
  const int quad = lane >> 4, l16 = lane & 15;
  const int bm = blockIdx.x * 128, bn = blockIdx.y * 128;
  const int wm = (wave >> 1) * 64, wn = (wave & 1) * 64;

  f32x4 acc[4][4] = {};

  for (int k0 = 0; k0 < K; k0 += 32) {
    __syncthreads();
    if constexpr (__is_same(TA, float)) {
#pragma unroll
      for (int i = 0; i < 2; ++i) {
        int c = tid + i * 256, row = c >> 2, col = (c & 3) << 3;
        *(bf16x8*)(&As[row * 32 + col]) =
            cvt8_f32_bf16(&A[(size_t)(bm + row) * K + k0 + col]);
      }
    } else {
#pragma unroll
      for (int t = 0; t < 2; ++t) {
        int chunk = wave * 128 + t * 64 + lane;
        int row = chunk >> 2, col = (chunk & 3) << 3;
        gld16(&A[(size_t)(bm + row) * K + k0 + col], &As[row * 32 + col]);
      }
    }
    if constexpr (__is_same(TW, float)) {
#pragma unroll
      for (int i = 0; i < 2; ++i) {
        int c = tid + i * 256, row = c >> 2, col = (c & 3) << 3;
        *(bf16x8*)(&Bs[row * 32 + col]) =
            cvt8_f32_bf16(&W[(size_t)(bn + row) * K + k0 + col]);
      }
    } else {
#pragma unroll
      for (int t = 0; t < 2; ++t) {
        int chunk = wave * 128 + t * 64 + lane;
        int row = chunk >> 2, col = (chunk & 3) << 3;
        gld16(&W[(size_t)(bn + row) * K + k0 + col], &Bs[row * 32 + col]);
      }
    }
    __syncthreads();
    bf16x8 af[4], bfr[4];
#pragma unroll
    for (int i = 0; i < 4; ++i) {
      af[i]  = *(const bf16x8*)(&As[(wm + i * 16 + l16) * 32 + quad * 8]);
      bfr[i] = *(const bf16x8*)(&Bs[(wn + i * 16 + l16) * 32 + quad * 8]);
    }
#pragma unroll
    for (int mi = 0; mi < 4; ++mi)
#pragma unroll
      for (int ni = 0; ni < 4; ++ni)
        acc[mi][ni] = __builtin_amdgcn_mfma_f32_16x16x32_bf16(
            af[mi], bfr[ni], acc[mi][ni], 0, 0, 0);
  }

#pragma unroll
  for (int mi = 0; mi < 4; ++mi) {
#pragma unroll
    for (int ni = 0; ni < 4; ++ni) {
      int col = bn + wn + ni * 16 + l16;
      float bval = bias[col];
      if (mode == 2) {
        int row0 = bm + wm + mi * 16 + quad * 4;
        int b = row0 >> 11, s = row0 & (S_LEN - 1);
        int h = col >> 7,  d = col & (DH - 1);
        size_t idx0 = (((size_t)(b * NH + h)) * DH + d) * S_LEN + s;
        if constexpr (__is_same(TC, bf16_t)) {
          bf16x4 o4;
#pragma unroll
          for (int r = 0; r < 4; ++r) o4[r] = (bf16_t)((acc[mi][ni][r] + bval) * oscale);
          *(bf16x4*)(&C[idx0]) = o4;
        } else {
#pragma unroll
          for (int r = 0; r < 4; ++r) C[idx0 + r] = (TC)((acc[mi][ni][r] + bval) * oscale);
        }
      } else {
#pragma unroll
        for (int r = 0; r < 4; ++r) {
          int row = bm + wm + mi * 16 + quad * 4 + r;
          float vv = (acc[mi][ni][r] + bval) * oscale;
          size_t idx;
          if (mode == 0) {
            idx = (size_t)row * N + col;
          } else {
            int b = row >> 11, s = row & (S_LEN - 1);
            int h = col >> 7,  d = col & (DH - 1);
            idx = (((size_t)(b * NH + h)) * S_LEN + s) * DH + d;
          }
          C[idx] = (TC)vv;
        }
      }
    }
  }
}

// ---------------- Flash attention, 32x32 swapped structure (R2 green) ------
// Q (pre-scaled by 1/sqrt(DH)*log2e): [B*NH,S,DH]  K: [B*NH,S,DH]
// V: [B*NH,DH,S]  O: [B,S,D]
// 4 waves x 32 q-rows = 128 q-rows/block; KVBLK=64; grid 512.
// Swapped QK^T (mfma(K,Q)): lane owns ONE q-row; softmax in-lane + shfl(32).
// P -> B-fragments rebuilt in-register via pack + shfl_xor(32) (no LDS Ps).
// K/V double-buffered in LDS via global_load_lds with XOR-swizzled SOURCE
// (rule #21: linear dest + inverse-swz source + swz read). ONE __syncthreads
// per tile; its vmcnt(0) is exactly the drain of the prefetch issued after
// the PREVIOUS barrier (full-tile overlap).
// NOTE R5 lesson: direct global V reads are UNCOALESCED (lane stride = row);
// coalesced gld16 staging + LDS re-read is strictly better here.
__global__ __launch_bounds__(256, 2)
void attn_fwd(const bf16_t* __restrict__ Q, const bf16_t* __restrict__ Kh,
              const bf16_t* __restrict__ Vt, bf16_t* __restrict__ O,
              const int* __restrict__ causal_p)
{
  __shared__ __align__(16) bf16_t Ks[2][64 * 128];   // [key][dh], src-swizzled
  __shared__ __align__(16) bf16_t Vs[2][128 * 64];   // [dh][key], src-swizzled
  const int tid  = threadIdx.x;
  const int wave = tid >> 6, lane = tid & 63;
  const int l31  = lane & 31, hi = lane >> 5;
  const int id = blockIdx.x;
  const int bh = id & 31;                       // XCD-pinned per head
  const int phase = id >> 5;                    // 0..15
  const int qb = (phase < 8) ? (15 - phase) : (phase - 8);
  const int causal = *causal_p;

  const bf16_t* Qb = Q  + (size_t)bh * S_LEN * DH;
  const bf16_t* Kb = Kh + (size_t)bh * S_LEN * DH;
  const bf16_t* Vb = Vt + (size_t)bh * DH * S_LEN;

  const int qrow   = qb * 128 + wave * 32 + l31;  // this lane's q row
  const int qmin_w = qb * 128 + wave * 32;        // wave-uniform

  // Q fragments (B-operand): lane gives Q[q=l31][kk*16 + hi*8 + j]
  bf16x8 qf[8];
#pragma unroll
  for (int kk = 0; kk < 8; ++kk)
    qf[kk] = *(const bf16x8*)(&Qb[(size_t)qrow * DH + kk * 16 + hi * 8]);

  f32x16 oacc[4] = {};           // O^T: D[dh-block][q], col=lane&31=q
  float mrow = NEG_BIG, lrow = 0.f;

  const int nkb = causal ? (2 * qb + 2) : (S_LEN / 64);

  // stage tile kb_ into buffer buf: 1024 16B-chunks each for K and V.
  // LDS linear; global source pre-swizzled: LDS(r,c) holds G(r, c^(r&7)).
  auto STAGE = [&](int buf, int kb_) {
#pragma unroll
    for (int i = 0; i < 4; ++i) {
      int c = tid + i * 256;
      int kr = c >> 4, kc = c & 15;
      gld16(&Kb[(size_t)(kb_ * 64 + kr) * DH + ((kc ^ (kr & 7)) << 3)],
            &Ks[buf][c << 3]);
      int vr = c >> 3, vc = c & 7;
      gld16(&Vb[(size_t)vr * S_LEN + kb_ * 64 + ((vc ^ (vr & 7)) << 3)],
            &Vs[buf][c << 3]);
    }
  };

  STAGE(0, 0);
  int cur = 0;
  for (int kb = 0; kb < nkb; ++kb) {
    // vmcnt(0)+fence+barrier: buf[cur] (prefetched last iter by ALL waves)
    // is now fully in LDS; buf[cur^1] is free for the next prefetch.
    __syncthreads();
    if (kb + 1 < nkb) STAGE(cur ^ 1, kb + 1);   // in flight over the compute

    if (!causal || (kb * 64 <= qmin_w + 31)) {  // wave-uniform tail skip
      const bf16_t* ks = &Ks[cur][0];
      const bf16_t* vs = &Vs[cur][0];

      // ---- S^T = K Q^T : D[key][q], 64 keys = 2 key-blocks x 16 regs ----
      f32x16 sc[2] = {};
#pragma unroll
      for (int kk = 0; kk < 8; ++kk) {
        int ch = ((kk << 1) | hi) ^ (l31 & 7);
        bf16x8 kf0 = *(const bf16x8*)(&ks[(l31) * 128 + ch * 8]);
        bf16x8 kf1 = *(const bf16x8*)(&ks[(32 + l31) * 128 + ch * 8]);
        sc[0] = __builtin_amdgcn_mfma_f32_32x32x16_bf16(kf0, qf[kk], sc[0], 0, 0, 0);
        sc[1] = __builtin_amdgcn_mfma_f32_32x32x16_bf16(kf1, qf[kk], sc[1], 0, 0, 0);
      }

      // ---- causal mask (boundary tiles only; per-lane q, per-reg key) ----
      // C/D row formula (m74/m101): row32 = (r&3) + 8*(r>>2) + 4*hi
      if (causal && (kb * 64 + 63 > qmin_w)) {
#pragma unroll
        for (int kblk = 0; kblk < 2; ++kblk)
#pragma unroll
          for (int r = 0; r < 16; ++r) {
            int key = kb * 64 + kblk * 32 + (r & 3) + 8 * (r >> 2) + 4 * hi;
            if (key > qrow) sc[kblk][r] = NEG_BIG;
          }
      }

      // ---- online softmax: in-lane over 32 regs + one shfl_xor(32) ----
      float pm = sc[0][0];
#pragma unroll
      for (int r = 1; r < 16; ++r) pm = fmaxf(pm, sc[0][r]);
#pragma unroll
      for (int r = 0; r < 16; ++r) pm = fmaxf(pm, sc[1][r]);
      pm = fmaxf(pm, __shfl_xor(pm, 32));
      float mnew  = fmaxf(mrow, pm);
      float alpha = exp2fast(mrow - mnew);
      mrow = mnew;
      float rs = 0.f;
#pragma unroll
      for (int kblk = 0; kblk < 2; ++kblk)
#pragma unroll
        for (int r = 0; r < 16; ++r) {
          float e = exp2fast(sc[kblk][r] - mnew);
          sc[kblk][r] = e;
          rs += e;
        }
      rs += __shfl_xor(rs, 32);
      lrow = lrow * alpha + rs;
#pragma unroll
      for (int d = 0; d < 4; ++d) oacc[d] *= alpha;

      // ---- P -> bf16 B-fragments in-register (pack + shfl_xor(32)) ----
      u32x4 pw[2][2];
#pragma unroll
      for (int kblk = 0; kblk < 2; ++kblk)
#pragma unroll
        for (int kc = 0; kc < 2; ++kc) {
          int b0 = kc * 8;
          u32 pa = pack_bf16(sc[kblk][b0 + 0], sc[kblk][b0 + 1]);
          u32 pc = pack_bf16(sc[kblk][b0 + 2], sc[kblk][b0 + 3]);
          u32 pb = pack_bf16(sc[kblk][b0 + 4], sc[kblk][b0 + 5]);
          u32 pd = pack_bf16(sc[kblk][b0 + 6], sc[kblk][b0 + 7]);
          u32 qa = (u32)__shfl_xor((int)pa, 32);
          u32 qb_ = (u32)__shfl_xor((int)pb, 32);
          u32 qc = (u32)__shfl_xor((int)pc, 32);
          u32 qd = (u32)__shfl_xor((int)pd, 32);
          u32x4 w;
          w[0] = hi ? qb_ : pa;
          w[1] = hi ? qd  : pc;
          w[2] = hi ? pb  : qa;
          w[3] = hi ? pd  : qc;
          pw[kblk][kc] = w;
        }

      // ---- O^T += V^T P : A = V^T rows=dh (from Vs), B = P frags ----
#pragma unroll
      for (int d = 0; d < 4; ++d) {
        int vrow = d * 32 + l31;
#pragma unroll
        for (int kblk = 0; kblk < 2; ++kblk)
#pragma unroll
          for (int kc = 0; kc < 2; ++kc) {
            bf16x8 vf = *(const bf16x8*)(
                &vs[vrow * 64 + ((((kblk << 2) | (kc << 1) | hi)) ^ (l31 & 7)) * 8]);
            bf16x8 pf = __builtin_bit_cast(bf16x8, pw[kblk][kc]);
            oacc[d] = __builtin_amdgcn_mfma_f32_32x32x16_bf16(vf, pf, oacc[d], 0, 0, 0);
          }
      }
    }
    cur ^= 1;
  }

  // ---- epilogue: O[q][dh]; dh = d*32 + g*8 + hi*4 + j (8B packed stores) --
  const int b = bh >> 4, h = bh & 15;
  float linv = 1.0f / fmaxf(lrow, 1e-20f);
  bf16_t* Ob = O + ((size_t)(b * S_LEN + qrow)) * DMODEL + h * DH;
#pragma unroll
  for (int d = 0; d < 4; ++d)
#pragma unroll
    for (int g = 0; g < 4; ++g) {
      bf16x4 o4;
#pragma unroll
      for (int j = 0; j < 4; ++j) o4[j] = (bf16_t)(oacc[d][g * 4 + j] * linv);
      *(bf16x4*)(&Ob[d * 32 + g * 8 + hi * 4]) = o4;
    }
}

extern "C" void kernel_launch(void* const* d_in, const int* in_sizes, int n_in,
                              void* d_out, int out_size, void* d_ws, size_t ws_size,
                              hipStream_t stream) {
  const float* q  = (const float*)d_in[0];
  const float* k  = (const float*)d_in[1];
  const float* v  = (const float*)d_in[2];
  const float* Wq = (const float*)d_in[3];
  const float* bq = (const float*)d_in[4];
  const float* Wk = (const float*)d_in[5];
  const float* bk = (const float*)d_in[6];
  const float* Wv = (const float*)d_in[7];
  const float* bv = (const float*)d_in[8];
  const float* Wo = (const float*)d_in[9];
  const float* bo = (const float*)d_in[10];
  const int*   cm = (const int*)d_in[11];

  float* out = (float*)d_out;
  const size_t NA = (size_t)MROWS * DMODEL;     // 8,388,608
  const size_t NW = (size_t)DMODEL * DMODEL;    // 4,194,304
  // 1/sqrt(128) * log2(e): scores land in exp2 domain (v_exp_f32 direct)
  const float qscale = 0.08838834764831845f * 1.4426950408889634f;

  bf16_t* p0 = (bf16_t*)d_ws;
  const size_t needA = (4 * NW + 7 * NA) * sizeof(bf16_t);  // ~151 MB
  const size_t needB = (4 * NW + 4 * NA) * sizeof(bf16_t);  // ~101 MB

  dim3 gg(MROWS / 128, DMODEL / 128), bb(256);
  dim3 g3(MROWS / 128, DMODEL / 128, 3);
  dim3 ga(512);
  bf16_t *Qh, *Kh, *Vh, *Ao;

  if (ws_size >= needA) {
    bf16_t *Wqb = p0;                       // 4 contiguous NW regions
    bf16_t *qb2 = p0 + 4 * NW;              // 3 contiguous NA regions
    bf16_t *kb2 = qb2 + NA, *vb2 = kb2 + NA;
    Qh = vb2 + NA; Kh = Qh + NA; Vh = Kh + NA; Ao = Vh + NA;
    cvt_bf16_w4<<<dim3(4 * (int)(NW / 2048)), bb, 0, stream>>>(
        Wq, Wk, Wv, Wo, Wqb, (int)(NW / 2048));
    cvt_bf16_a3<<<dim3(3 * (int)(NA / 2048)), bb, 0, stream>>>(
        q, k, v, qb2, (int)(NA / 2048));
    qkv_gemm<<<g3, bb, 0, stream>>>(qb2, Wqb, bq, bk, bv, Qh, qscale);
    attn_fwd<<<ga, bb, 0, stream>>>(Qh, Kh, Vh, Ao, cm);
    gemm_bt<bf16_t, bf16_t, float><<<gg, bb, 0, stream>>>(Ao, Wqb + 3 * NW, bo, out, 0, 1.0f);
  } else if (ws_size >= needB) {
    bf16_t *Wqb = p0;
    Qh = p0 + 4 * NW; Kh = Qh + NA; Vh = Kh + NA; Ao = Vh + NA;
    cvt_bf16_w4<<<dim3(4 * (int)(NW / 2048)), bb, 0, stream>>>(
        Wq, Wk, Wv, Wo, Wqb, (int)(NW / 2048));
    gemm_bt<float, bf16_t, bf16_t><<<gg, bb, 0, stream>>>(q, Wqb,          bq, Qh, 1, qscale);
    gemm_bt<float, bf16_t, bf16_t><<<gg, bb, 0, stream>>>(k, Wqb + NW,     bk, Kh, 1, 1.0f);
    gemm_bt<float, bf16_t, bf16_t><<<gg, bb, 0, stream>>>(v, Wqb + 2 * NW, bv, Vh, 2, 1.0f);
    attn_fwd<<<ga, bb, 0, stream>>>(Qh, Kh, Vh, Ao, cm);
    gemm_bt<bf16_t, bf16_t, float><<<gg, bb, 0, stream>>>(Ao, Wqb + 3 * NW, bo, out, 0, 1.0f);
  } else {
    Qh = p0; Kh = Qh + NA; Vh = Kh + NA; Ao = Vh + NA;
    gemm_bt<float, float, bf16_t><<<gg, bb, 0, stream>>>(q, Wq, bq, Qh, 1, qscale);
    gemm_bt<float, float, bf16_t><<<gg, bb, 0, stream>>>(k, Wk, bk, Kh, 1, 1.0f);
    gemm_bt<float, float, bf16_t><<<gg, bb, 0, stream>>>(v, Wv, bv, Vh, 2, 1.0f);
    attn_fwd<<<ga, bb, 0, stream>>>(Qh, Kh, Vh, Ao, cm);
    gemm_bt<bf16_t, float, float><<<gg, bb, 0, stream>>>(Ao, Wo, bo, out, 0, 1.0f);
  }
}